// Round 10
// baseline (186.818 us; speedup 1.0000x reference)
//
#include <hip/hip_runtime.h>
#include <math.h>

// SS2D (VMamba v2) forward — MI355X gfx950.
// fp32 core; MFMA bf16-split in-proj; MFMA bf16 out-proj fused into scan3.
//
// Pipeline (6 dispatches):
//  k_castW   : W_in -> (hi,lo) bf16; W_out -> bf16
//  k_inproj3 : xz = x @ W_in^T via 3-term bf16 MFMA split (x split inline)
//  k_conv8   : depthwise 3x3 SAME + bias + silu -> xg (scan order)
//  k_scan1g  : x_dbl GEMM into LDS (rows<22) + local scan -> S (sum dlt), Q
//  k_scan2   : prefix over 64 chunks; P recomputed as exp(A*S)
//  k_scan3gl : x_dbl GEMM + replay with true h_in + LayerNorm + gate
//              + MFMA out GEMM, all in one block (no yout round-trip)

#define DINNER 192
#define NSTATE 16
#define KDIR 4
#define BATCH 4
#define NPIX (BATCH * 64 * 64)          // 16384
#define LP 1024
#define NCH 64                          // scan chunks
#define CHUNK 16                        // LP / NCH
#define NBK (BATCH * KDIR)              // 16
#define NSTATES (NBK * DINNER * NSTATE) // 49152
#define SSTRIDE (NBK * DINNER)          // 3072 floats of S per chunk
#define USTRIDE 196                     // sU row stride (floats)
#define GSTRIDE 200                     // bf16 g LDS stride (shorts)

typedef __attribute__((ext_vector_type(8))) short short8;
typedef __attribute__((ext_vector_type(4))) float f32x4;

__device__ __forceinline__ float silu_f(float x) {
    return x / (1.0f + __expf(-x));
}
__device__ __forceinline__ float softplus_f(float a) {
    return (a > 20.0f) ? a : __logf(1.0f + __expf(a));
}
__device__ __forceinline__ unsigned short f2bf(float f) {
    unsigned u = __float_as_uint(f);
    unsigned r = (u + 0x7FFFu + ((u >> 16) & 1u)) >> 16;
    return (unsigned short)r;
}
__device__ __forceinline__ float bf2f(unsigned short h) {
    return __uint_as_float(((unsigned)h) << 16);
}

// Weights only: W_in hi/lo bf16 split (row-major), W_out bf16 cast.
__global__ __launch_bounds__(256) void k_castW(
        const float* __restrict__ W_in, const float* __restrict__ W_out,
        unsigned short* __restrict__ Wi_hi, unsigned short* __restrict__ Wi_lo,
        unsigned short* __restrict__ Wo_bf) {
    int i = blockIdx.x * 256 + threadIdx.x;
    if (i < 384 * 96) {
        float v = W_in[i];
        unsigned short h = f2bf(v);
        Wi_hi[i] = h;
        Wi_lo[i] = f2bf(v - bf2f(h));
    }
    if (i < 96 * DINNER) Wo_bf[i] = f2bf(W_out[i]);
}

// MFMA in-proj (bf16x3 split), x split inline from fp32.
// block = 16 pixels; wave w -> e-tiles w*6..w*6+5.
// A[m=lane&15][k=quad*8+j] = x[p0+m][c], B[k][n=lane&15] = W_in[e0+n][c].
// D: col=lane&15 (e), row=quad*4+reg (pixel).   err ~ x_lo*W_lo ~ 1e-5.
__global__ __launch_bounds__(256) void k_inproj3(
        const float* __restrict__ x,
        const unsigned short* __restrict__ Wi_hi,
        const unsigned short* __restrict__ Wi_lo,
        float* __restrict__ xin, float* __restrict__ z) {
    int p0 = blockIdx.x * 16;
    int w = threadIdx.x >> 6;
    int lane = threadIdx.x & 63;
    int m = lane & 15, quad = lane >> 4;
    const short* wh = (const short*)Wi_hi;
    const short* wl = (const short*)Wi_lo;
    short8 ah[3], al[3];
    #pragma unroll
    for (int c = 0; c < 3; ++c) {
        const float* xr = x + (size_t)(p0 + m) * 96 + c * 32 + quad * 8;
        short8 hi, lo;
        #pragma unroll
        for (int j = 0; j < 8; ++j) {
            float v = xr[j];
            unsigned short hb = f2bf(v);
            hi[j] = (short)hb;
            lo[j] = (short)f2bf(v - bf2f(hb));
        }
        ah[c] = hi;
        al[c] = lo;
    }
    #pragma unroll
    for (int i = 0; i < 6; ++i) {
        int e0 = (w * 6 + i) * 16;
        f32x4 acc = {0.f, 0.f, 0.f, 0.f};
        #pragma unroll
        for (int c = 0; c < 3; ++c) {
            size_t o = (size_t)(e0 + m) * 96 + c * 32 + quad * 8;
            short8 bh = *(const short8*)(wh + o);
            short8 bl = *(const short8*)(wl + o);
            acc = __builtin_amdgcn_mfma_f32_16x16x32_bf16(ah[c], bl, acc, 0, 0, 0);
            acc = __builtin_amdgcn_mfma_f32_16x16x32_bf16(al[c], bh, acc, 0, 0, 0);
            acc = __builtin_amdgcn_mfma_f32_16x16x32_bf16(ah[c], bh, acc, 0, 0, 0);
        }
        int e = e0 + m;
        #pragma unroll
        for (int r = 0; r < 4; ++r) {
            int p = p0 + quad * 4 + r;
            if (e < 192) xin[(size_t)p * 192 + e] = acc[r];
            else         z[(size_t)p * 192 + (e - 192)] = silu_f(acc[r]);
        }
    }
}

// depthwise 3x3, 8 consecutive pixels of one row per block; sliding-window loads.
// Output in scan order xg[(bk*1024+l)*192+d].
__global__ __launch_bounds__(192) void k_conv8(
        const float* __restrict__ xin, const float* __restrict__ cw,
        const float* __restrict__ cb, float* __restrict__ xg) {
    int blk = blockIdx.x;             // 2048 = 4 b * 64 h * 8 wchunks
    int b = blk >> 9;
    int rem = blk & 511;
    int h = rem >> 3;
    int w0 = (rem & 7) * 8;
    int d = threadIdx.x;
    float wr[3][3];
    #pragma unroll
    for (int i = 0; i < 3; ++i)
        #pragma unroll
        for (int j = 0; j < 3; ++j) wr[i][j] = cw[d * 9 + i * 3 + j];
    float bias = cb[d];
    float acc[8];
    #pragma unroll
    for (int o = 0; o < 8; ++o) acc[o] = bias;
    #pragma unroll
    for (int jj = 0; jj < 10; ++jj) {
        int ww = w0 + jj - 1;
        float r0 = 0.0f, r1 = 0.0f, r2 = 0.0f;
        if ((unsigned)ww < 64u) {
            const float* base = xin + ((size_t)b * 4096 + h * 64 + ww) * 192 + d;
            if (h > 0)  r0 = base[-64 * 192];
            r1 = base[0];
            if (h < 63) r2 = base[64 * 192];
        }
        #pragma unroll
        for (int dd2 = 0; dd2 < 3; ++dd2) {
            int o = jj - 2 + dd2;
            int cj = 2 - dd2;
            if (o >= 0 && o < 8) {
                acc[o] = fmaf(r0, wr[0][cj], acc[o]);
                acc[o] = fmaf(r1, wr[1][cj], acc[o]);
                acc[o] = fmaf(r2, wr[2][cj], acc[o]);
            }
        }
    }
    #pragma unroll
    for (int o = 0; o < 8; ++o) {
        int w = w0 + o;
        int kq = (h & 1) ? ((w & 1) ? 3 : 1) : ((w & 1) ? 2 : 0);
        int l = (kq & 1) ? ((w >> 1) * 32 + (h >> 1))
                         : ((h >> 1) * 32 + (w >> 1));
        xg[((size_t)(b * 4 + kq) * 1024 + l) * 192 + d] = silu_f(acc[o]);
    }
}

// Pass 1 (fused x_dbl): u tile + GEMM rows<22 into LDS, local scan.
// Emits Q (chunk-local h) and S = sum(dlt) per (ch, bk, d)  [P = exp(A*S)].
__global__ __launch_bounds__(192) void k_scan1g(
        const float* __restrict__ xg, const float* __restrict__ xpw,
        const float* __restrict__ A_logs, const float* __restrict__ dtw,
        const float* __restrict__ dtb,
        float* __restrict__ Sbuf, float* __restrict__ Qbuf) {
    __shared__ float sU[CHUNK * USTRIDE];
    __shared__ float sB[CHUNK * 16];
    __shared__ float sR[CHUNK * 8];
    int bk = blockIdx.x >> 6;
    int ch = blockIdx.x & 63;
    int k = bk & 3;
    int t = threadIdx.x;
    int d = t;
    int lbase = bk * 1024 + ch * CHUNK;
    const float4* usrc = (const float4*)(xg + (size_t)lbase * 192);
    for (int i = t; i < CHUNK * 48; i += 192) {
        int l = i / 48, c4 = i - l * 48;
        *(float4*)&sU[l * USTRIDE + c4 * 4] = usrc[i];
    }
    float A[16];
    #pragma unroll
    for (int n = 0; n < 16; ++n) A[n] = -__expf(A_logs[(k * 192 + d) * 16 + n]);
    float A0 = A[0];
    bool geo = true;                 // A[n] == (n+1)*A[0] (geometric ladder)?
    #pragma unroll
    for (int n = 1; n < 16; ++n)
        geo = geo && (fabsf(A[n] - (float)(n + 1) * A0) <= 1e-4f * fabsf(A[n]));
    float wp[6];
    #pragma unroll
    for (int q = 0; q < 6; ++q) wp[q] = dtw[(k * 192 + d) * 6 + q];
    float bias = dtb[k * 192 + d];
    __syncthreads();
    {
        int l = t & 15, cgp = t >> 4;       // 16 l x 12 c-groups
        float acc0 = 0.0f, acc1 = 0.0f;
        const float* wb = xpw + (size_t)k * 38 * 192;
        int c1 = cgp + 12;
        int c1r = (c1 < 22) ? c1 : cgp;
        for (int qv = 0; qv < 48; ++qv) {
            float4 xv = *(const float4*)&sU[l * USTRIDE + qv * 4];
            float4 w0 = *(const float4*)&wb[(size_t)cgp * 192 + qv * 4];
            float4 w1 = *(const float4*)&wb[(size_t)c1r * 192 + qv * 4];
            acc0 = fmaf(xv.x, w0.x, fmaf(xv.y, w0.y, fmaf(xv.z, w0.z, fmaf(xv.w, w0.w, acc0))));
            acc1 = fmaf(xv.x, w1.x, fmaf(xv.y, w1.y, fmaf(xv.z, w1.z, fmaf(xv.w, w1.w, acc1))));
        }
        if (cgp < 6) sR[l * 8 + cgp] = acc0;
        else         sB[l * 16 + (cgp - 6)] = acc0;
        if (c1 < 22) sB[l * 16 + (c1 - 6)] = acc1;
    }
    __syncthreads();
    float h[16];
    #pragma unroll
    for (int n = 0; n < 16; ++n) h[n] = 0.0f;
    float S = 0.0f;
    for (int l = 0; l < CHUNK; ++l) {
        float a = bias;
        #pragma unroll
        for (int q = 0; q < 6; ++q) a = fmaf(wp[q], sR[l * 8 + q], a);
        float dlt = softplus_f(a);
        S += dlt;
        float du = dlt * sU[l * USTRIDE + d];
        if (geo) {
            float e1 = __expf(dlt * A0);
            float e = e1;
            #pragma unroll
            for (int n = 0; n < 16; ++n) {
                h[n] = fmaf(e, h[n], du * sB[l * 16 + n]);
                e *= e1;
            }
        } else {
            #pragma unroll
            for (int n = 0; n < 16; ++n) {
                float e = __expf(dlt * A[n]);
                h[n] = fmaf(e, h[n], du * sB[l * 16 + n]);
            }
        }
    }
    Sbuf[(size_t)ch * SSTRIDE + bk * 192 + d] = S;
    size_t base = (size_t)ch * NSTATES + bk * (192 * 16);
    #pragma unroll
    for (int n = 0; n < 16; ++n)
        Qbuf[base + n * 192 + d] = h[n];
}

// Pass 2: prefix over chunks; P recomputed as exp(A*S). In place (QH -> h_start).
__global__ __launch_bounds__(256) void k_scan2(
        const float* __restrict__ Sbuf, const float* __restrict__ A_logs,
        float* QH) {
    int s = blockIdx.x * 256 + threadIdx.x;   // 0..NSTATES-1
    int bk = s / 3072;                         // 3072 = 16*192
    int rem = s - bk * 3072;
    int n = rem / 192;
    int d = rem - n * 192;
    int k = bk & 3;
    float A = -__expf(A_logs[(k * 192 + d) * 16 + n]);
    float h = 0.0f;
    for (int c = 0; c < NCH; ++c) {
        float q = QH[(size_t)c * NSTATES + s];
        float S = Sbuf[(size_t)c * SSTRIDE + bk * 192 + d];
        float p = __expf(A * S);
        QH[(size_t)c * NSTATES + s] = h;
        h = fmaf(p, h, q);
    }
}

// Pass 3: x_dbl GEMM + replay with true h_in + LayerNorm + gate + MFMA out-proj.
// y rows stay in LDS (sU overwritten in place); no yout round-trip.
__global__ __launch_bounds__(192) void k_scan3gl(
        const float* __restrict__ xg, const float* __restrict__ xpw,
        const float* __restrict__ A_logs, const float* __restrict__ dtw,
        const float* __restrict__ dtb, const float* __restrict__ Ds,
        const float* __restrict__ QH, const float* __restrict__ zbuf,
        const float* __restrict__ lng, const float* __restrict__ lnb,
        const unsigned short* __restrict__ Wo_bf, float* __restrict__ out) {
    __shared__ float sU[CHUNK * USTRIDE];   // u tile -> y rows (in place)
    __shared__ float sB[CHUNK * 16];
    __shared__ float sC[CHUNK * 16];
    __shared__ float sR[CHUNK * 8];
    __shared__ float red[2][12][16];
    __shared__ float smv[2][16];            // mu, rstd per row
    __shared__ int   spix[16];              // pixel index per row
    __shared__ __align__(16) short sA[CHUNK * GSTRIDE];  // bf16 g rows
    int bk = blockIdx.x >> 6;
    int ch = blockIdx.x & 63;
    int k = bk & 3;
    int t = threadIdx.x;
    int d = t;
    int lbase = bk * 1024 + ch * CHUNK;
    const float4* usrc = (const float4*)(xg + (size_t)lbase * 192);
    for (int i = t; i < CHUNK * 48; i += 192) {
        int l = i / 48, c4 = i - l * 48;
        *(float4*)&sU[l * USTRIDE + c4 * 4] = usrc[i];
    }
    float A[16];
    #pragma unroll
    for (int n = 0; n < 16; ++n) A[n] = -__expf(A_logs[(k * 192 + d) * 16 + n]);
    float A0 = A[0];
    bool geo = true;
    #pragma unroll
    for (int n = 1; n < 16; ++n)
        geo = geo && (fabsf(A[n] - (float)(n + 1) * A0) <= 1e-4f * fabsf(A[n]));
    float wp[6];
    #pragma unroll
    for (int q = 0; q < 6; ++q) wp[q] = dtw[(k * 192 + d) * 6 + q];
    float bias = dtb[k * 192 + d];
    float Dp = Ds[k * 192 + d];
    __syncthreads();
    // ---- x_dbl GEMM: all 38 rows into sR/sB/sC ----
    {
        int l = t & 15, cgp = t >> 4;
        float acc[4] = {0.f, 0.f, 0.f, 0.f};
        int c3 = (cgp < 2) ? (cgp + 36) : cgp;
        const float* wb = xpw + (size_t)k * 38 * 192;
        for (int qv = 0; qv < 48; ++qv) {
            float4 xv = *(const float4*)&sU[l * USTRIDE + qv * 4];
            float4 w0 = *(const float4*)&wb[(cgp +  0) * 192 + qv * 4];
            float4 w1 = *(const float4*)&wb[(cgp + 12) * 192 + qv * 4];
            float4 w2 = *(const float4*)&wb[(cgp + 24) * 192 + qv * 4];
            float4 w3 = *(const float4*)&wb[(size_t)c3 * 192 + qv * 4];
            acc[0] = fmaf(xv.x, w0.x, fmaf(xv.y, w0.y, fmaf(xv.z, w0.z, fmaf(xv.w, w0.w, acc[0]))));
            acc[1] = fmaf(xv.x, w1.x, fmaf(xv.y, w1.y, fmaf(xv.z, w1.z, fmaf(xv.w, w1.w, acc[1]))));
            acc[2] = fmaf(xv.x, w2.x, fmaf(xv.y, w2.y, fmaf(xv.z, w2.z, fmaf(xv.w, w2.w, acc[2]))));
            acc[3] = fmaf(xv.x, w3.x, fmaf(xv.y, w3.y, fmaf(xv.z, w3.z, fmaf(xv.w, w3.w, acc[3]))));
        }
        #pragma unroll
        for (int j = 0; j < 4; ++j) {
            int c = cgp + 12 * j;
            if (j == 3) { if (cgp >= 2) break; c = cgp + 36; }
            float v = acc[j];
            if (c < 6)       sR[l * 8 + c] = v;
            else if (c < 22) sB[l * 16 + (c - 6)] = v;
            else             sC[l * 16 + (c - 22)] = v;
        }
    }
    float h[16];
    size_t base = (size_t)ch * NSTATES + bk * (192 * 16);
    #pragma unroll
    for (int n = 0; n < 16; ++n) h[n] = QH[base + n * 192 + d];
    __syncthreads();
    // ---- replay; write y into sU in place (each (l,d) owned by thread d) ----
    for (int l = 0; l < CHUNK; ++l) {
        float a = bias;
        #pragma unroll
        for (int q = 0; q < 6; ++q) a = fmaf(wp[q], sR[l * 8 + q], a);
        float dlt = softplus_f(a);
        float u = sU[l * USTRIDE + d];
        float du = dlt * u;
        float y = 0.0f;
        if (geo) {
            float e1 = __expf(dlt * A0);
            float e = e1;
            #pragma unroll
            for (int n = 0; n < 16; ++n) {
                h[n] = fmaf(e, h[n], du * sB[l * 16 + n]);
                y = fmaf(h[n], sC[l * 16 + n], y);
                e *= e1;
            }
        } else {
            #pragma unroll
            for (int n = 0; n < 16; ++n) {
                float e = __expf(dlt * A[n]);
                h[n] = fmaf(e, h[n], du * sB[l * 16 + n]);
                y = fmaf(h[n], sC[l * 16 + n], y);
            }
        }
        sU[l * USTRIDE + d] = fmaf(u, Dp, y);
    }
    __syncthreads();
    // ---- LayerNorm stats: 12 segments x 16 rows ----
    {
        int lq = t & 15, seg = t >> 4;
        float ps = 0.0f, ps2 = 0.0f;
        #pragma unroll
        for (int j = 0; j < 16; ++j) {
            float v = sU[lq * USTRIDE + seg * 16 + j];
            ps += v;
            ps2 += v * v;
        }
        red[0][seg][lq] = ps;
        red[1][seg][lq] = ps2;
    }
    __syncthreads();
    if (t < 16) {
        float s = 0.0f, s2 = 0.0f;
        #pragma unroll
        for (int sg = 0; sg < 12; ++sg) { s += red[0][sg][t]; s2 += red[1][sg][t]; }
        float mu = s * (1.0f / 192.0f);
        float var = s2 * (1.0f / 192.0f) - mu * mu;
        smv[0][t] = mu;
        smv[1][t] = rsqrtf(var + 1e-5f);
    }
    __syncthreads();
    // ---- gate + bf16 -> sA ----
    {
        float lg = lng[d], lb = lnb[d];
        int b = bk >> 2;
        for (int l = 0; l < CHUNK; ++l) {
            int gl = ch * CHUNK + l;
            int i = gl >> 5, j = gl & 31;
            int hh, wpx;
            if (k == 0)      { hh = 2 * i;     wpx = 2 * j;     }
            else if (k == 1) { hh = 2 * j + 1; wpx = 2 * i;     }
            else if (k == 2) { hh = 2 * i;     wpx = 2 * j + 1; }
            else             { hh = 2 * j + 1; wpx = 2 * i + 1; }
            int p = b * 4096 + hh * 64 + wpx;
            if (d == 0) spix[l] = p;
            float y = sU[l * USTRIDE + d];
            float g = ((y - smv[0][l]) * smv[1][l] * lg + lb) * zbuf[(size_t)p * 192 + d];
            sA[l * GSTRIDE + d] = (short)f2bf(g);
        }
    }
    __syncthreads();
    // ---- MFMA out GEMM: out[16 x 96] = g @ W_out^T; 3 waves x 2 N-tiles ----
    {
        int wv = t >> 6;
        int lane = t & 63;
        int m = lane & 15, quad = lane >> 4;
        const short* wob = (const short*)Wo_bf;
        short8 a[6];
        #pragma unroll
        for (int kk = 0; kk < 6; ++kk)
            a[kk] = *(const short8*)(sA + m * GSTRIDE + kk * 32 + quad * 8);
        #pragma unroll
        for (int i2 = 0; i2 < 2; ++i2) {
            int n0 = (wv * 2 + i2) * 16;
            f32x4 acc = {0.f, 0.f, 0.f, 0.f};
            #pragma unroll
            for (int kk = 0; kk < 6; ++kk) {
                short8 bfr = *(const short8*)(wob + (size_t)(n0 + m) * 192 + kk * 32 + quad * 8);
                acc = __builtin_amdgcn_mfma_f32_16x16x32_bf16(a[kk], bfr, acc, 0, 0, 0);
            }
            #pragma unroll
            for (int r = 0; r < 4; ++r) {
                int l = quad * 4 + r;
                out[(size_t)spix[l] * 96 + n0 + m] = acc[r];
            }
        }
    }
}

extern "C" void kernel_launch(void* const* d_in, const int* in_sizes, int n_in,
                              void* d_out, int out_size, void* d_ws, size_t ws_size,
                              hipStream_t stream) {
    const float* x    = (const float*)d_in[0];
    const float* W_in = (const float*)d_in[1];
    const float* cw   = (const float*)d_in[2];
    const float* cb   = (const float*)d_in[3];
    const float* xpw  = (const float*)d_in[4];
    const float* dtw  = (const float*)d_in[5];
    const float* dtb  = (const float*)d_in[6];
    const float* Alog = (const float*)d_in[7];
    const float* Ds   = (const float*)d_in[8];
    const float* lng  = (const float*)d_in[9];
    const float* lnb  = (const float*)d_in[10];
    const float* Wout = (const float*)d_in[11];
    float* out = (float*)d_out;

    float* ws = (float*)d_ws;
    size_t off = 0;
    unsigned short* Wi_hi = (unsigned short*)(ws + off); off += 384 * 96 / 2;
    unsigned short* Wi_lo = (unsigned short*)(ws + off); off += 384 * 96 / 2;
    unsigned short* Wo_bf = (unsigned short*)(ws + off); off += 96 * DINNER / 2;
    float* xin   = ws + off; off += (size_t)NPIX * 192;
    float* zbuf  = ws + off; off += (size_t)NPIX * 192;
    float* xg    = ws + off; off += (size_t)NPIX * 192;
    float* Sbuf  = ws + off; off += (size_t)NCH * SSTRIDE;
    float* QH    = ws + off; off += (size_t)NCH * NSTATES;

    hipLaunchKernelGGL(k_castW, dim3(144), dim3(256), 0, stream,
                       W_in, Wout, Wi_hi, Wi_lo, Wo_bf);
    hipLaunchKernelGGL(k_inproj3, dim3(NPIX / 16), dim3(256), 0, stream,
                       x, Wi_hi, Wi_lo, xin, zbuf);
    hipLaunchKernelGGL(k_conv8, dim3(NPIX / 8), dim3(192), 0, stream,
                       xin, cw, cb, xg);
    hipLaunchKernelGGL(k_scan1g, dim3(NBK * NCH), dim3(192), 0, stream,
                       xg, xpw, Alog, dtw, dtb, Sbuf, QH);
    hipLaunchKernelGGL(k_scan2, dim3(NSTATES / 256), dim3(256), 0, stream,
                       Sbuf, Alog, QH);
    hipLaunchKernelGGL(k_scan3gl, dim3(NBK * NCH), dim3(192), 0, stream,
                       xg, xpw, Alog, dtw, dtb, Ds, QH, zbuf, lng, lnb,
                       Wo_bf, out);
}

// Round 11
// 182.086 us; speedup vs baseline: 1.0260x; 1.0260x over previous
//
#include <hip/hip_runtime.h>
#include <math.h>

// SS2D (VMamba v2) forward — MI355X gfx950.
// fp32 core; MFMA bf16-split in-proj (x split inline); MFMA bf16 out-proj.
//
// Pipeline (7 dispatches):
//  k_castW   : W_in -> (hi,lo) bf16; W_out -> bf16
//  k_inproj3 : xz = x @ W_in^T via 3-term bf16 MFMA split
//  k_conv8   : depthwise 3x3 SAME + bias + silu -> xg (scan order)
//  k_scan1g  : per 8-step chunk: x_dbl GEMM into LDS (rows<22) + local scan
//  k_scan2   : prefix over 128 chunks; P recomputed as exp(A*S)
//  k_scan3g  : x_dbl GEMM recompute (38 rows) + replay with true h_in -> yout
//  k_lnout   : merge + LayerNorm + gate -> bf16 LDS -> MFMA out GEMM
//
// NCH=128 (CHUNK=8): 2048 scan blocks -> ~6.5 blocks/CU resident (was 4),
// attacking the measured latency-bound regime (VALUBusy 25%, Occ 14%).

#define DINNER 192
#define NSTATE 16
#define KDIR 4
#define BATCH 4
#define NPIX (BATCH * 64 * 64)          // 16384
#define LP 1024
#define NCH 128                         // scan chunks
#define CHUNK 8                         // LP / NCH
#define NBK (BATCH * KDIR)              // 16
#define NSTATES (NBK * DINNER * NSTATE) // 49152
#define SSTRIDE (NBK * DINNER)          // 3072 floats of S per chunk
#define USTRIDE 196                     // sU row stride (floats)
#define GSTRIDE 200                     // lnout bf16 g LDS stride (shorts)

typedef __attribute__((ext_vector_type(8))) short short8;
typedef __attribute__((ext_vector_type(4))) short short4v;
typedef __attribute__((ext_vector_type(4))) float f32x4;

__device__ __forceinline__ float silu_f(float x) {
    return x / (1.0f + __expf(-x));
}
__device__ __forceinline__ float softplus_f(float a) {
    return (a > 20.0f) ? a : __logf(1.0f + __expf(a));
}
__device__ __forceinline__ unsigned short f2bf(float f) {
    unsigned u = __float_as_uint(f);
    unsigned r = (u + 0x7FFFu + ((u >> 16) & 1u)) >> 16;
    return (unsigned short)r;
}
__device__ __forceinline__ float bf2f(unsigned short h) {
    return __uint_as_float(((unsigned)h) << 16);
}

// Weights only: W_in hi/lo bf16 split (row-major), W_out bf16 cast.
__global__ __launch_bounds__(256) void k_castW(
        const float* __restrict__ W_in, const float* __restrict__ W_out,
        unsigned short* __restrict__ Wi_hi, unsigned short* __restrict__ Wi_lo,
        unsigned short* __restrict__ Wo_bf) {
    int i = blockIdx.x * 256 + threadIdx.x;
    if (i < 384 * 96) {
        float v = W_in[i];
        unsigned short h = f2bf(v);
        Wi_hi[i] = h;
        Wi_lo[i] = f2bf(v - bf2f(h));
    }
    if (i < 96 * DINNER) Wo_bf[i] = f2bf(W_out[i]);
}

// MFMA in-proj (bf16x3 split), x split inline from fp32.
__global__ __launch_bounds__(256) void k_inproj3(
        const float* __restrict__ x,
        const unsigned short* __restrict__ Wi_hi,
        const unsigned short* __restrict__ Wi_lo,
        float* __restrict__ xin, float* __restrict__ z) {
    int p0 = blockIdx.x * 16;
    int w = threadIdx.x >> 6;
    int lane = threadIdx.x & 63;
    int m = lane & 15, quad = lane >> 4;
    const short* wh = (const short*)Wi_hi;
    const short* wl = (const short*)Wi_lo;
    short8 ah[3], al[3];
    #pragma unroll
    for (int c = 0; c < 3; ++c) {
        const float* xr = x + (size_t)(p0 + m) * 96 + c * 32 + quad * 8;
        short8 hi, lo;
        #pragma unroll
        for (int j = 0; j < 8; ++j) {
            float v = xr[j];
            unsigned short hb = f2bf(v);
            hi[j] = (short)hb;
            lo[j] = (short)f2bf(v - bf2f(hb));
        }
        ah[c] = hi;
        al[c] = lo;
    }
    #pragma unroll
    for (int i = 0; i < 6; ++i) {
        int e0 = (w * 6 + i) * 16;
        f32x4 acc = {0.f, 0.f, 0.f, 0.f};
        #pragma unroll
        for (int c = 0; c < 3; ++c) {
            size_t o = (size_t)(e0 + m) * 96 + c * 32 + quad * 8;
            short8 bh = *(const short8*)(wh + o);
            short8 bl = *(const short8*)(wl + o);
            acc = __builtin_amdgcn_mfma_f32_16x16x32_bf16(ah[c], bl, acc, 0, 0, 0);
            acc = __builtin_amdgcn_mfma_f32_16x16x32_bf16(al[c], bh, acc, 0, 0, 0);
            acc = __builtin_amdgcn_mfma_f32_16x16x32_bf16(ah[c], bh, acc, 0, 0, 0);
        }
        int e = e0 + m;
        #pragma unroll
        for (int r = 0; r < 4; ++r) {
            int p = p0 + quad * 4 + r;
            if (e < 192) xin[(size_t)p * 192 + e] = acc[r];
            else         z[(size_t)p * 192 + (e - 192)] = silu_f(acc[r]);
        }
    }
}

// depthwise 3x3, 8 consecutive pixels of one row per block; sliding-window loads.
__global__ __launch_bounds__(192) void k_conv8(
        const float* __restrict__ xin, const float* __restrict__ cw,
        const float* __restrict__ cb, float* __restrict__ xg) {
    int blk = blockIdx.x;             // 2048 = 4 b * 64 h * 8 wchunks
    int b = blk >> 9;
    int rem = blk & 511;
    int h = rem >> 3;
    int w0 = (rem & 7) * 8;
    int d = threadIdx.x;
    float wr[3][3];
    #pragma unroll
    for (int i = 0; i < 3; ++i)
        #pragma unroll
        for (int j = 0; j < 3; ++j) wr[i][j] = cw[d * 9 + i * 3 + j];
    float bias = cb[d];
    float acc[8];
    #pragma unroll
    for (int o = 0; o < 8; ++o) acc[o] = bias;
    #pragma unroll
    for (int jj = 0; jj < 10; ++jj) {
        int ww = w0 + jj - 1;
        float r0 = 0.0f, r1 = 0.0f, r2 = 0.0f;
        if ((unsigned)ww < 64u) {
            const float* base = xin + ((size_t)b * 4096 + h * 64 + ww) * 192 + d;
            if (h > 0)  r0 = base[-64 * 192];
            r1 = base[0];
            if (h < 63) r2 = base[64 * 192];
        }
        #pragma unroll
        for (int dd2 = 0; dd2 < 3; ++dd2) {
            int o = jj - 2 + dd2;
            int cj = 2 - dd2;
            if (o >= 0 && o < 8) {
                acc[o] = fmaf(r0, wr[0][cj], acc[o]);
                acc[o] = fmaf(r1, wr[1][cj], acc[o]);
                acc[o] = fmaf(r2, wr[2][cj], acc[o]);
            }
        }
    }
    #pragma unroll
    for (int o = 0; o < 8; ++o) {
        int w = w0 + o;
        int kq = (h & 1) ? ((w & 1) ? 3 : 1) : ((w & 1) ? 2 : 0);
        int l = (kq & 1) ? ((w >> 1) * 32 + (h >> 1))
                         : ((h >> 1) * 32 + (w >> 1));
        xg[((size_t)(b * 4 + kq) * 1024 + l) * 192 + d] = silu_f(acc[o]);
    }
}

// Pass 1 (fused x_dbl): u tile + GEMM rows<22 into LDS, local scan.
// Emits Q (chunk-local h) and S = sum(dlt).  8 l-rows x 24 c-groups.
__global__ __launch_bounds__(192) void k_scan1g(
        const float* __restrict__ xg, const float* __restrict__ xpw,
        const float* __restrict__ A_logs, const float* __restrict__ dtw,
        const float* __restrict__ dtb,
        float* __restrict__ Sbuf, float* __restrict__ Qbuf) {
    __shared__ float sU[CHUNK * USTRIDE];
    __shared__ float sB[CHUNK * 16];
    __shared__ float sR[CHUNK * 8];
    int bk = blockIdx.x >> 7;
    int ch = blockIdx.x & 127;
    int k = bk & 3;
    int t = threadIdx.x;
    int d = t;
    int lbase = bk * 1024 + ch * CHUNK;
    const float4* usrc = (const float4*)(xg + (size_t)lbase * 192);
    for (int i = t; i < CHUNK * 48; i += 192) {
        int l = i / 48, c4 = i - l * 48;
        *(float4*)&sU[l * USTRIDE + c4 * 4] = usrc[i];
    }
    float A[16];
    #pragma unroll
    for (int n = 0; n < 16; ++n) A[n] = -__expf(A_logs[(k * 192 + d) * 16 + n]);
    float A0 = A[0];
    bool geo = true;                 // A[n] == (n+1)*A[0] (geometric ladder)?
    #pragma unroll
    for (int n = 1; n < 16; ++n)
        geo = geo && (fabsf(A[n] - (float)(n + 1) * A0) <= 1e-4f * fabsf(A[n]));
    float wp[6];
    #pragma unroll
    for (int q = 0; q < 6; ++q) wp[q] = dtw[(k * 192 + d) * 6 + q];
    float bias = dtb[k * 192 + d];
    __syncthreads();
    {
        int l = t & 7, cgp = t >> 3;        // 8 l x 24 c-groups (rows 0..21 used)
        float acc0 = 0.0f;
        const float* wb = xpw + (size_t)k * 38 * 192;
        int c0 = (cgp < 22) ? cgp : 0;
        for (int qv = 0; qv < 48; ++qv) {
            float4 xv = *(const float4*)&sU[l * USTRIDE + qv * 4];
            float4 w0 = *(const float4*)&wb[(size_t)c0 * 192 + qv * 4];
            acc0 = fmaf(xv.x, w0.x, fmaf(xv.y, w0.y, fmaf(xv.z, w0.z, fmaf(xv.w, w0.w, acc0))));
        }
        if (cgp < 6)       sR[l * 8 + cgp] = acc0;
        else if (cgp < 22) sB[l * 16 + (cgp - 6)] = acc0;
    }
    __syncthreads();
    float h[16];
    #pragma unroll
    for (int n = 0; n < 16; ++n) h[n] = 0.0f;
    float S = 0.0f;
    for (int l = 0; l < CHUNK; ++l) {
        float a = bias;
        #pragma unroll
        for (int q = 0; q < 6; ++q) a = fmaf(wp[q], sR[l * 8 + q], a);
        float dlt = softplus_f(a);
        S += dlt;
        float du = dlt * sU[l * USTRIDE + d];
        if (geo) {
            float e1 = __expf(dlt * A0);
            float e = e1;
            #pragma unroll
            for (int n = 0; n < 16; ++n) {
                h[n] = fmaf(e, h[n], du * sB[l * 16 + n]);
                e *= e1;
            }
        } else {
            #pragma unroll
            for (int n = 0; n < 16; ++n) {
                float e = __expf(dlt * A[n]);
                h[n] = fmaf(e, h[n], du * sB[l * 16 + n]);
            }
        }
    }
    Sbuf[(size_t)ch * SSTRIDE + bk * 192 + d] = S;
    size_t base = (size_t)ch * NSTATES + bk * (192 * 16);
    #pragma unroll
    for (int n = 0; n < 16; ++n)
        Qbuf[base + n * 192 + d] = h[n];
}

// Pass 2: prefix over chunks; P recomputed as exp(A*S). In place (QH -> h_start).
__global__ __launch_bounds__(256) void k_scan2(
        const float* __restrict__ Sbuf, const float* __restrict__ A_logs,
        float* QH) {
    int s = blockIdx.x * 256 + threadIdx.x;   // 0..NSTATES-1
    int bk = s / 3072;                         // 3072 = 16*192
    int rem = s - bk * 3072;
    int n = rem / 192;
    int d = rem - n * 192;
    int k = bk & 3;
    float A = -__expf(A_logs[(k * 192 + d) * 16 + n]);
    float h = 0.0f;
    for (int c = 0; c < NCH; ++c) {
        float q = QH[(size_t)c * NSTATES + s];
        float S = Sbuf[(size_t)c * SSTRIDE + bk * 192 + d];
        float p = __expf(A * S);
        QH[(size_t)c * NSTATES + s] = h;
        h = fmaf(p, h, q);
    }
}

// Pass 3 (fused x_dbl): GEMM recompute (38 rows: cgp + cgp+24), replay -> yout.
__global__ __launch_bounds__(192) void k_scan3g(
        const float* __restrict__ xg, const float* __restrict__ xpw,
        const float* __restrict__ A_logs, const float* __restrict__ dtw,
        const float* __restrict__ dtb, const float* __restrict__ Ds,
        const float* __restrict__ QH, float* __restrict__ yout) {
    __shared__ float sU[CHUNK * USTRIDE];
    __shared__ float sB[CHUNK * 16];
    __shared__ float sC[CHUNK * 16];
    __shared__ float sR[CHUNK * 8];
    int bk = blockIdx.x >> 7;
    int ch = blockIdx.x & 127;
    int k = bk & 3;
    int t = threadIdx.x;
    int d = t;
    int lbase = bk * 1024 + ch * CHUNK;
    const float4* usrc = (const float4*)(xg + (size_t)lbase * 192);
    for (int i = t; i < CHUNK * 48; i += 192) {
        int l = i / 48, c4 = i - l * 48;
        *(float4*)&sU[l * USTRIDE + c4 * 4] = usrc[i];
    }
    float A[16];
    #pragma unroll
    for (int n = 0; n < 16; ++n) A[n] = -__expf(A_logs[(k * 192 + d) * 16 + n]);
    float A0 = A[0];
    bool geo = true;
    #pragma unroll
    for (int n = 1; n < 16; ++n)
        geo = geo && (fabsf(A[n] - (float)(n + 1) * A0) <= 1e-4f * fabsf(A[n]));
    float wp[6];
    #pragma unroll
    for (int q = 0; q < 6; ++q) wp[q] = dtw[(k * 192 + d) * 6 + q];
    float bias = dtb[k * 192 + d];
    float Dp = Ds[k * 192 + d];
    __syncthreads();
    {
        int l = t & 7, cgp = t >> 3;        // 8 l x 24 c-groups; rows cgp, cgp+24
        float acc0 = 0.0f, acc1 = 0.0f;
        const float* wb = xpw + (size_t)k * 38 * 192;
        int c1 = cgp + 24;
        int c1r = (c1 < 38) ? c1 : cgp;
        for (int qv = 0; qv < 48; ++qv) {
            float4 xv = *(const float4*)&sU[l * USTRIDE + qv * 4];
            float4 w0 = *(const float4*)&wb[(size_t)cgp * 192 + qv * 4];
            float4 w1 = *(const float4*)&wb[(size_t)c1r * 192 + qv * 4];
            acc0 = fmaf(xv.x, w0.x, fmaf(xv.y, w0.y, fmaf(xv.z, w0.z, fmaf(xv.w, w0.w, acc0))));
            acc1 = fmaf(xv.x, w1.x, fmaf(xv.y, w1.y, fmaf(xv.z, w1.z, fmaf(xv.w, w1.w, acc1))));
        }
        if (cgp < 6)       sR[l * 8 + cgp] = acc0;
        else if (cgp < 22) sB[l * 16 + (cgp - 6)] = acc0;
        else               sC[l * 16 + (cgp - 22)] = acc0;
        if (c1 < 38)       sC[l * 16 + (c1 - 22)] = acc1;
    }
    float h[16];
    size_t base = (size_t)ch * NSTATES + bk * (192 * 16);
    #pragma unroll
    for (int n = 0; n < 16; ++n) h[n] = QH[base + n * 192 + d];
    __syncthreads();
    for (int l = 0; l < CHUNK; ++l) {
        float a = bias;
        #pragma unroll
        for (int q = 0; q < 6; ++q) a = fmaf(wp[q], sR[l * 8 + q], a);
        float dlt = softplus_f(a);
        float u = sU[l * USTRIDE + d];
        float du = dlt * u;
        float y = 0.0f;
        if (geo) {
            float e1 = __expf(dlt * A0);
            float e = e1;
            #pragma unroll
            for (int n = 0; n < 16; ++n) {
                h[n] = fmaf(e, h[n], du * sB[l * 16 + n]);
                y = fmaf(h[n], sC[l * 16 + n], y);
                e *= e1;
            }
        } else {
            #pragma unroll
            for (int n = 0; n < 16; ++n) {
                float e = __expf(dlt * A[n]);
                h[n] = fmaf(e, h[n], du * sB[l * 16 + n]);
                y = fmaf(h[n], sC[l * 16 + n], y);
            }
        }
        yout[(size_t)(lbase + l) * 192 + d] = fmaf(u, Dp, y);
    }
}

// merge + LayerNorm + gate -> g (bf16, LDS) -> MFMA out GEMM. 32 pixels/block.
__global__ __launch_bounds__(256) void k_lnout(
        const float* __restrict__ yout, const float* __restrict__ z,
        const float* __restrict__ lng, const float* __restrict__ lnb,
        const unsigned short* __restrict__ Wo_bf, float* __restrict__ out) {
    __shared__ __align__(16) short sgb[32 * GSTRIDE];
    int p0 = blockIdx.x * 32;
    int t = threadIdx.x;
    int p = t >> 3;                    // pixel 0..31
    int sub = t & 7;                   // 8 threads per pixel, 24 channels each
    int gp = p0 + p;
    int b = gp >> 12;
    int hw = gp & 4095;
    int h = hw >> 6, w = hw & 63;
    int kq = (h & 1) ? ((w & 1) ? 3 : 1) : ((w & 1) ? 2 : 0);
    int l = (kq & 1) ? ((w >> 1) * 32 + (h >> 1))
                     : ((h >> 1) * 32 + (w >> 1));
    const float* yrow = yout + ((size_t)(b * 4 + kq) * 1024 + l) * 192 + sub * 24;
    float4 yv[6];
    float s = 0.0f, s2 = 0.0f;
    #pragma unroll
    for (int j = 0; j < 6; ++j) {
        float4 v = *(const float4*)(yrow + j * 4);
        yv[j] = v;
        s += v.x + v.y + v.z + v.w;
        s2 += v.x * v.x + v.y * v.y + v.z * v.z + v.w * v.w;
    }
    #pragma unroll
    for (int off = 1; off < 8; off <<= 1) {
        s  += __shfl_xor(s, off, 8);
        s2 += __shfl_xor(s2, off, 8);
    }
    float mu = s * (1.0f / 192.0f);
    float var = s2 * (1.0f / 192.0f) - mu * mu;
    float rstd = rsqrtf(var + 1e-5f);
    const float* zrow = z + (size_t)gp * 192 + sub * 24;
    short* grow = sgb + p * GSTRIDE + sub * 24;
    #pragma unroll
    for (int j = 0; j < 6; ++j) {
        float4 zv = *(const float4*)(zrow + j * 4);
        float4 gv = *(const float4*)(lng + sub * 24 + j * 4);
        float4 bv = *(const float4*)(lnb + sub * 24 + j * 4);
        short4v sv;
        sv.x = (short)f2bf(((yv[j].x - mu) * rstd * gv.x + bv.x) * zv.x);
        sv.y = (short)f2bf(((yv[j].y - mu) * rstd * gv.y + bv.y) * zv.y);
        sv.z = (short)f2bf(((yv[j].z - mu) * rstd * gv.z + bv.z) * zv.z);
        sv.w = (short)f2bf(((yv[j].w - mu) * rstd * gv.w + bv.w) * zv.w);
        *(short4v*)(grow + j * 4) = sv;
    }
    __syncthreads();
    int wv = t >> 6;
    int lane = t & 63;
    int m = lane & 15, quad = lane >> 4;
    int mt = wv >> 1;
    int nb = (wv & 1) * 3;
    const short* wob = (const short*)Wo_bf;
    short8 a[6];
    #pragma unroll
    for (int kk = 0; kk < 6; ++kk)
        a[kk] = *(const short8*)(sgb + (mt * 16 + m) * GSTRIDE + kk * 32 + quad * 8);
    #pragma unroll
    for (int i = 0; i < 3; ++i) {
        int n0 = (nb + i) * 16;
        f32x4 acc = {0.f, 0.f, 0.f, 0.f};
        #pragma unroll
        for (int kk = 0; kk < 6; ++kk) {
            short8 bfr = *(const short8*)(wob + (size_t)(n0 + m) * 192 + kk * 32 + quad * 8);
            acc = __builtin_amdgcn_mfma_f32_16x16x32_bf16(a[kk], bfr, acc, 0, 0, 0);
        }
        #pragma unroll
        for (int r = 0; r < 4; ++r) {
            int pp = p0 + mt * 16 + quad * 4 + r;
            out[(size_t)pp * 96 + n0 + m] = acc[r];
        }
    }
}

extern "C" void kernel_launch(void* const* d_in, const int* in_sizes, int n_in,
                              void* d_out, int out_size, void* d_ws, size_t ws_size,
                              hipStream_t stream) {
    const float* x    = (const float*)d_in[0];
    const float* W_in = (const float*)d_in[1];
    const float* cw   = (const float*)d_in[2];
    const float* cb   = (const float*)d_in[3];
    const float* xpw  = (const float*)d_in[4];
    const float* dtw  = (const float*)d_in[5];
    const float* dtb  = (const float*)d_in[6];
    const float* Alog = (const float*)d_in[7];
    const float* Ds   = (const float*)d_in[8];
    const float* lng  = (const float*)d_in[9];
    const float* lnb  = (const float*)d_in[10];
    const float* Wout = (const float*)d_in[11];
    float* out = (float*)d_out;

    float* ws = (float*)d_ws;
    size_t off = 0;
    unsigned short* Wi_hi = (unsigned short*)(ws + off); off += 384 * 96 / 2;
    unsigned short* Wi_lo = (unsigned short*)(ws + off); off += 384 * 96 / 2;
    unsigned short* Wo_bf = (unsigned short*)(ws + off); off += 96 * DINNER / 2;
    float* xin   = ws + off; off += (size_t)NPIX * 192;
    float* zbuf  = ws + off; off += (size_t)NPIX * 192;
    float* xg    = ws + off; off += (size_t)NPIX * 192;
    float* Sbuf  = ws + off; off += (size_t)NCH * SSTRIDE;
    float* QH    = ws + off; off += (size_t)NCH * NSTATES;
    float* yout  = ws + off; off += (size_t)NBK * LP * 192;

    hipLaunchKernelGGL(k_castW, dim3(144), dim3(256), 0, stream,
                       W_in, Wout, Wi_hi, Wi_lo, Wo_bf);
    hipLaunchKernelGGL(k_inproj3, dim3(NPIX / 16), dim3(256), 0, stream,
                       x, Wi_hi, Wi_lo, xin, zbuf);
    hipLaunchKernelGGL(k_conv8, dim3(NPIX / 8), dim3(192), 0, stream,
                       xin, cw, cb, xg);
    hipLaunchKernelGGL(k_scan1g, dim3(NBK * NCH), dim3(192), 0, stream,
                       xg, xpw, Alog, dtw, dtb, Sbuf, QH);
    hipLaunchKernelGGL(k_scan2, dim3(NSTATES / 256), dim3(256), 0, stream,
                       Sbuf, Alog, QH);
    hipLaunchKernelGGL(k_scan3g, dim3(NBK * NCH), dim3(192), 0, stream,
                       xg, xpw, Alog, dtw, dtb, Ds, QH, yout);
    hipLaunchKernelGGL(k_lnout, dim3(NPIX / 32), dim3(256), 0, stream,
                       yout, zbuf, lng, lnb, Wo_bf, out);
}

// Round 12
// 173.954 us; speedup vs baseline: 1.0739x; 1.0467x over previous
//
#include <hip/hip_runtime.h>
#include <math.h>

// SS2D (VMamba v2) forward — MI355X gfx950.
// fp32 core; MFMA bf16-split in-proj (x split inline); MFMA bf16 out-proj.
//
// Pipeline (8 dispatches):
//  k_castW   : W_in -> (hi,lo) bf16; W_out -> bf16
//  k_inproj3 : xz = x @ W_in^T via 3-term bf16 MFMA split
//  k_conv8   : depthwise 3x3 SAME + bias + silu -> xg (scan order)
//  k_xdbl    : x_dbl GEMM ONCE -> dtr/Bm/Cm (was fused+recomputed in both scans)
//  k_scan1p  : PURE scan per 16-step chunk -> S (sum dlt), Q   [no GEMM phase]
//  k_scan2   : prefix over 64 chunks; P recomputed as exp(A*S)
//  k_scan3p  : PURE scan replay with true h_in -> yout          [no GEMM phase]
//  k_lnout   : merge + LayerNorm + gate -> bf16 LDS -> MFMA out GEMM

#define DINNER 192
#define NSTATE 16
#define KDIR 4
#define BATCH 4
#define NPIX (BATCH * 64 * 64)          // 16384
#define LP 1024
#define NCH 64                          // scan chunks
#define CHUNK 16                        // LP / NCH
#define NBK (BATCH * KDIR)              // 16
#define NSTATES (NBK * DINNER * NSTATE) // 49152
#define SSTRIDE (NBK * DINNER)          // 3072 floats of S per chunk
#define USTRIDE 196                     // sU row stride (floats)
#define GSTRIDE 200                     // lnout bf16 g LDS stride (shorts)

typedef __attribute__((ext_vector_type(8))) short short8;
typedef __attribute__((ext_vector_type(4))) short short4v;
typedef __attribute__((ext_vector_type(4))) float f32x4;

__device__ __forceinline__ float silu_f(float x) {
    return x / (1.0f + __expf(-x));
}
__device__ __forceinline__ float softplus_f(float a) {
    return (a > 20.0f) ? a : __logf(1.0f + __expf(a));
}
__device__ __forceinline__ unsigned short f2bf(float f) {
    unsigned u = __float_as_uint(f);
    unsigned r = (u + 0x7FFFu + ((u >> 16) & 1u)) >> 16;
    return (unsigned short)r;
}
__device__ __forceinline__ float bf2f(unsigned short h) {
    return __uint_as_float(((unsigned)h) << 16);
}

// Weights only: W_in hi/lo bf16 split (row-major), W_out bf16 cast.
__global__ __launch_bounds__(256) void k_castW(
        const float* __restrict__ W_in, const float* __restrict__ W_out,
        unsigned short* __restrict__ Wi_hi, unsigned short* __restrict__ Wi_lo,
        unsigned short* __restrict__ Wo_bf) {
    int i = blockIdx.x * 256 + threadIdx.x;
    if (i < 384 * 96) {
        float v = W_in[i];
        unsigned short h = f2bf(v);
        Wi_hi[i] = h;
        Wi_lo[i] = f2bf(v - bf2f(h));
    }
    if (i < 96 * DINNER) Wo_bf[i] = f2bf(W_out[i]);
}

// MFMA in-proj (bf16x3 split), x split inline from fp32.
__global__ __launch_bounds__(256) void k_inproj3(
        const float* __restrict__ x,
        const unsigned short* __restrict__ Wi_hi,
        const unsigned short* __restrict__ Wi_lo,
        float* __restrict__ xin, float* __restrict__ z) {
    int p0 = blockIdx.x * 16;
    int w = threadIdx.x >> 6;
    int lane = threadIdx.x & 63;
    int m = lane & 15, quad = lane >> 4;
    const short* wh = (const short*)Wi_hi;
    const short* wl = (const short*)Wi_lo;
    short8 ah[3], al[3];
    #pragma unroll
    for (int c = 0; c < 3; ++c) {
        const float* xr = x + (size_t)(p0 + m) * 96 + c * 32 + quad * 8;
        short8 hi, lo;
        #pragma unroll
        for (int j = 0; j < 8; ++j) {
            float v = xr[j];
            unsigned short hb = f2bf(v);
            hi[j] = (short)hb;
            lo[j] = (short)f2bf(v - bf2f(hb));
        }
        ah[c] = hi;
        al[c] = lo;
    }
    #pragma unroll
    for (int i = 0; i < 6; ++i) {
        int e0 = (w * 6 + i) * 16;
        f32x4 acc = {0.f, 0.f, 0.f, 0.f};
        #pragma unroll
        for (int c = 0; c < 3; ++c) {
            size_t o = (size_t)(e0 + m) * 96 + c * 32 + quad * 8;
            short8 bh = *(const short8*)(wh + o);
            short8 bl = *(const short8*)(wl + o);
            acc = __builtin_amdgcn_mfma_f32_16x16x32_bf16(ah[c], bl, acc, 0, 0, 0);
            acc = __builtin_amdgcn_mfma_f32_16x16x32_bf16(al[c], bh, acc, 0, 0, 0);
            acc = __builtin_amdgcn_mfma_f32_16x16x32_bf16(ah[c], bh, acc, 0, 0, 0);
        }
        int e = e0 + m;
        #pragma unroll
        for (int r = 0; r < 4; ++r) {
            int p = p0 + quad * 4 + r;
            if (e < 192) xin[(size_t)p * 192 + e] = acc[r];
            else         z[(size_t)p * 192 + (e - 192)] = silu_f(acc[r]);
        }
    }
}

// depthwise 3x3, 8 consecutive pixels of one row per block; sliding-window loads.
__global__ __launch_bounds__(192) void k_conv8(
        const float* __restrict__ xin, const float* __restrict__ cw,
        const float* __restrict__ cb, float* __restrict__ xg) {
    int blk = blockIdx.x;             // 2048 = 4 b * 64 h * 8 wchunks
    int b = blk >> 9;
    int rem = blk & 511;
    int h = rem >> 3;
    int w0 = (rem & 7) * 8;
    int d = threadIdx.x;
    float wr[3][3];
    #pragma unroll
    for (int i = 0; i < 3; ++i)
        #pragma unroll
        for (int j = 0; j < 3; ++j) wr[i][j] = cw[d * 9 + i * 3 + j];
    float bias = cb[d];
    float acc[8];
    #pragma unroll
    for (int o = 0; o < 8; ++o) acc[o] = bias;
    #pragma unroll
    for (int jj = 0; jj < 10; ++jj) {
        int ww = w0 + jj - 1;
        float r0 = 0.0f, r1 = 0.0f, r2 = 0.0f;
        if ((unsigned)ww < 64u) {
            const float* base = xin + ((size_t)b * 4096 + h * 64 + ww) * 192 + d;
            if (h > 0)  r0 = base[-64 * 192];
            r1 = base[0];
            if (h < 63) r2 = base[64 * 192];
        }
        #pragma unroll
        for (int dd2 = 0; dd2 < 3; ++dd2) {
            int o = jj - 2 + dd2;
            int cj = 2 - dd2;
            if (o >= 0 && o < 8) {
                acc[o] = fmaf(r0, wr[0][cj], acc[o]);
                acc[o] = fmaf(r1, wr[1][cj], acc[o]);
                acc[o] = fmaf(r2, wr[2][cj], acc[o]);
            }
        }
    }
    #pragma unroll
    for (int o = 0; o < 8; ++o) {
        int w = w0 + o;
        int kq = (h & 1) ? ((w & 1) ? 3 : 1) : ((w & 1) ? 2 : 0);
        int l = (kq & 1) ? ((w >> 1) * 32 + (h >> 1))
                         : ((h >> 1) * 32 + (w >> 1));
        xg[((size_t)(b * 4 + kq) * 1024 + l) * 192 + d] = silu_f(acc[o]);
    }
}

// x_dbl GEMM once: per (bk, 16-l tile), 38 rows -> dtr/Bm/Cm.
// 192 threads = 16 l x 12 c-groups; rows cgp, cgp+12, cgp+24, cgp+36(<2).
__global__ __launch_bounds__(192) void k_xdbl(
        const float* __restrict__ xg, const float* __restrict__ xpw,
        float* __restrict__ dtr, float* __restrict__ Bm, float* __restrict__ Cm) {
    __shared__ float sU[16 * USTRIDE];
    int bk = blockIdx.x >> 6;
    int tile = blockIdx.x & 63;
    int k = bk & 3;
    int t = threadIdx.x;
    int lbase = bk * 1024 + tile * 16;
    const float4* usrc = (const float4*)(xg + (size_t)lbase * 192);
    for (int i = t; i < 16 * 48; i += 192) {
        int l = i / 48, c4 = i - l * 48;
        *(float4*)&sU[l * USTRIDE + c4 * 4] = usrc[i];
    }
    __syncthreads();
    int l = t & 15, cgp = t >> 4;
    float acc[4] = {0.f, 0.f, 0.f, 0.f};
    int c3 = (cgp < 2) ? (cgp + 36) : cgp;
    const float* wb = xpw + (size_t)k * 38 * 192;
    for (int qv = 0; qv < 48; ++qv) {
        float4 xv = *(const float4*)&sU[l * USTRIDE + qv * 4];
        float4 w0 = *(const float4*)&wb[(cgp +  0) * 192 + qv * 4];
        float4 w1 = *(const float4*)&wb[(cgp + 12) * 192 + qv * 4];
        float4 w2 = *(const float4*)&wb[(cgp + 24) * 192 + qv * 4];
        float4 w3 = *(const float4*)&wb[(size_t)c3 * 192 + qv * 4];
        acc[0] = fmaf(xv.x, w0.x, fmaf(xv.y, w0.y, fmaf(xv.z, w0.z, fmaf(xv.w, w0.w, acc[0]))));
        acc[1] = fmaf(xv.x, w1.x, fmaf(xv.y, w1.y, fmaf(xv.z, w1.z, fmaf(xv.w, w1.w, acc[1]))));
        acc[2] = fmaf(xv.x, w2.x, fmaf(xv.y, w2.y, fmaf(xv.z, w2.z, fmaf(xv.w, w2.w, acc[2]))));
        acc[3] = fmaf(xv.x, w3.x, fmaf(xv.y, w3.y, fmaf(xv.z, w3.z, fmaf(xv.w, w3.w, acc[3]))));
    }
    int bkl = lbase + l;
    #pragma unroll
    for (int j = 0; j < 4; ++j) {
        int c = cgp + 12 * j;
        if (j == 3) { if (cgp >= 2) break; c = cgp + 36; }
        float v = acc[j];
        if (c < 6)       dtr[(size_t)bkl * 6 + c] = v;
        else if (c < 22) Bm[(size_t)bkl * 16 + (c - 6)] = v;
        else             Cm[(size_t)bkl * 16 + (c - 22)] = v;
    }
}

// Pass 1: PURE scan. Stage u+B; dtr via wave-uniform loads; dlt inline.
__global__ __launch_bounds__(192) void k_scan1p(
        const float* __restrict__ xg, const float* __restrict__ dtr,
        const float* __restrict__ Bm, const float* __restrict__ A_logs,
        const float* __restrict__ dtw, const float* __restrict__ dtb,
        float* __restrict__ Sbuf, float* __restrict__ Qbuf) {
    __shared__ float sU[CHUNK * USTRIDE];
    __shared__ float sB[CHUNK * 16];
    int bk = blockIdx.x >> 6;
    int ch = blockIdx.x & 63;
    int k = bk & 3;
    int d = threadIdx.x;
    int lbase = bk * 1024 + ch * CHUNK;
    const float4* usrc = (const float4*)(xg + (size_t)lbase * 192);
    for (int i = d; i < CHUNK * 48; i += 192) {
        int l = i / 48, c4 = i - l * 48;
        *(float4*)&sU[l * USTRIDE + c4 * 4] = usrc[i];
    }
    for (int i = d; i < CHUNK * 16; i += 192) sB[i] = Bm[(size_t)lbase * 16 + i];
    float A[16];
    #pragma unroll
    for (int n = 0; n < 16; ++n) A[n] = -__expf(A_logs[(k * 192 + d) * 16 + n]);
    float A0 = A[0];
    bool geo = true;                 // A[n] == (n+1)*A[0] (geometric ladder)?
    #pragma unroll
    for (int n = 1; n < 16; ++n)
        geo = geo && (fabsf(A[n] - (float)(n + 1) * A0) <= 1e-4f * fabsf(A[n]));
    float wp[6];
    #pragma unroll
    for (int q = 0; q < 6; ++q) wp[q] = dtw[(k * 192 + d) * 6 + q];
    float bias = dtb[k * 192 + d];
    __syncthreads();
    float h[16];
    #pragma unroll
    for (int n = 0; n < 16; ++n) h[n] = 0.0f;
    float S = 0.0f;
    for (int l = 0; l < CHUNK; ++l) {
        const float* r = dtr + (size_t)(lbase + l) * 6;   // wave-uniform
        float a = bias;
        #pragma unroll
        for (int q = 0; q < 6; ++q) a = fmaf(wp[q], r[q], a);
        float dlt = softplus_f(a);
        S += dlt;
        float du = dlt * sU[l * USTRIDE + d];
        if (geo) {
            float e1 = __expf(dlt * A0);
            float e = e1;
            #pragma unroll
            for (int n = 0; n < 16; ++n) {
                h[n] = fmaf(e, h[n], du * sB[l * 16 + n]);
                e *= e1;
            }
        } else {
            #pragma unroll
            for (int n = 0; n < 16; ++n) {
                float e = __expf(dlt * A[n]);
                h[n] = fmaf(e, h[n], du * sB[l * 16 + n]);
            }
        }
    }
    Sbuf[(size_t)ch * SSTRIDE + bk * 192 + d] = S;
    size_t base = (size_t)ch * NSTATES + bk * (192 * 16);
    #pragma unroll
    for (int n = 0; n < 16; ++n)
        Qbuf[base + n * 192 + d] = h[n];
}

// Pass 2: prefix over chunks; P recomputed as exp(A*S). In place (QH -> h_start).
__global__ __launch_bounds__(256) void k_scan2(
        const float* __restrict__ Sbuf, const float* __restrict__ A_logs,
        float* QH) {
    int s = blockIdx.x * 256 + threadIdx.x;   // 0..NSTATES-1
    int bk = s / 3072;                         // 3072 = 16*192
    int rem = s - bk * 3072;
    int n = rem / 192;
    int d = rem - n * 192;
    int k = bk & 3;
    float A = -__expf(A_logs[(k * 192 + d) * 16 + n]);
    float h = 0.0f;
    for (int c = 0; c < NCH; ++c) {
        float q = QH[(size_t)c * NSTATES + s];
        float S = Sbuf[(size_t)c * SSTRIDE + bk * 192 + d];
        float p = __expf(A * S);
        QH[(size_t)c * NSTATES + s] = h;
        h = fmaf(p, h, q);
    }
}

// Pass 3: PURE scan replay with true h_in -> yout.
__global__ __launch_bounds__(192) void k_scan3p(
        const float* __restrict__ xg, const float* __restrict__ dtr,
        const float* __restrict__ Bm, const float* __restrict__ Cm,
        const float* __restrict__ A_logs, const float* __restrict__ dtw,
        const float* __restrict__ dtb, const float* __restrict__ Ds,
        const float* __restrict__ QH, float* __restrict__ yout) {
    __shared__ float sU[CHUNK * USTRIDE];
    __shared__ float sB[CHUNK * 16];
    __shared__ float sC[CHUNK * 16];
    int bk = blockIdx.x >> 6;
    int ch = blockIdx.x & 63;
    int k = bk & 3;
    int d = threadIdx.x;
    int lbase = bk * 1024 + ch * CHUNK;
    const float4* usrc = (const float4*)(xg + (size_t)lbase * 192);
    for (int i = d; i < CHUNK * 48; i += 192) {
        int l = i / 48, c4 = i - l * 48;
        *(float4*)&sU[l * USTRIDE + c4 * 4] = usrc[i];
    }
    for (int i = d; i < CHUNK * 16; i += 192) {
        sB[i] = Bm[(size_t)lbase * 16 + i];
        sC[i] = Cm[(size_t)lbase * 16 + i];
    }
    float A[16];
    #pragma unroll
    for (int n = 0; n < 16; ++n) A[n] = -__expf(A_logs[(k * 192 + d) * 16 + n]);
    float A0 = A[0];
    bool geo = true;
    #pragma unroll
    for (int n = 1; n < 16; ++n)
        geo = geo && (fabsf(A[n] - (float)(n + 1) * A0) <= 1e-4f * fabsf(A[n]));
    float wp[6];
    #pragma unroll
    for (int q = 0; q < 6; ++q) wp[q] = dtw[(k * 192 + d) * 6 + q];
    float bias = dtb[k * 192 + d];
    float Dp = Ds[k * 192 + d];
    float h[16];
    size_t base = (size_t)ch * NSTATES + bk * (192 * 16);
    #pragma unroll
    for (int n = 0; n < 16; ++n) h[n] = QH[base + n * 192 + d];
    __syncthreads();
    for (int l = 0; l < CHUNK; ++l) {
        const float* r = dtr + (size_t)(lbase + l) * 6;   // wave-uniform
        float a = bias;
        #pragma unroll
        for (int q = 0; q < 6; ++q) a = fmaf(wp[q], r[q], a);
        float dlt = softplus_f(a);
        float u = sU[l * USTRIDE + d];
        float du = dlt * u;
        float y = 0.0f;
        if (geo) {
            float e1 = __expf(dlt * A0);
            float e = e1;
            #pragma unroll
            for (int n = 0; n < 16; ++n) {
                h[n] = fmaf(e, h[n], du * sB[l * 16 + n]);
                y = fmaf(h[n], sC[l * 16 + n], y);
                e *= e1;
            }
        } else {
            #pragma unroll
            for (int n = 0; n < 16; ++n) {
                float e = __expf(dlt * A[n]);
                h[n] = fmaf(e, h[n], du * sB[l * 16 + n]);
                y = fmaf(h[n], sC[l * 16 + n], y);
            }
        }
        yout[(size_t)(lbase + l) * 192 + d] = fmaf(u, Dp, y);
    }
}

// merge + LayerNorm + gate -> g (bf16, LDS) -> MFMA out GEMM. 32 pixels/block.
__global__ __launch_bounds__(256) void k_lnout(
        const float* __restrict__ yout, const float* __restrict__ z,
        const float* __restrict__ lng, const float* __restrict__ lnb,
        const unsigned short* __restrict__ Wo_bf, float* __restrict__ out) {
    __shared__ __align__(16) short sgb[32 * GSTRIDE];
    int p0 = blockIdx.x * 32;
    int t = threadIdx.x;
    int p = t >> 3;                    // pixel 0..31
    int sub = t & 7;                   // 8 threads per pixel, 24 channels each
    int gp = p0 + p;
    int b = gp >> 12;
    int hw = gp & 4095;
    int h = hw >> 6, w = hw & 63;
    int kq = (h & 1) ? ((w & 1) ? 3 : 1) : ((w & 1) ? 2 : 0);
    int l = (kq & 1) ? ((w >> 1) * 32 + (h >> 1))
                     : ((h >> 1) * 32 + (w >> 1));
    const float* yrow = yout + ((size_t)(b * 4 + kq) * 1024 + l) * 192 + sub * 24;
    float4 yv[6];
    float s = 0.0f, s2 = 0.0f;
    #pragma unroll
    for (int j = 0; j < 6; ++j) {
        float4 v = *(const float4*)(yrow + j * 4);
        yv[j] = v;
        s += v.x + v.y + v.z + v.w;
        s2 += v.x * v.x + v.y * v.y + v.z * v.z + v.w * v.w;
    }
    #pragma unroll
    for (int off = 1; off < 8; off <<= 1) {
        s  += __shfl_xor(s, off, 8);
        s2 += __shfl_xor(s2, off, 8);
    }
    float mu = s * (1.0f / 192.0f);
    float var = s2 * (1.0f / 192.0f) - mu * mu;
    float rstd = rsqrtf(var + 1e-5f);
    const float* zrow = z + (size_t)gp * 192 + sub * 24;
    short* grow = sgb + p * GSTRIDE + sub * 24;
    #pragma unroll
    for (int j = 0; j < 6; ++j) {
        float4 zv = *(const float4*)(zrow + j * 4);
        float4 gv = *(const float4*)(lng + sub * 24 + j * 4);
        float4 bv = *(const float4*)(lnb + sub * 24 + j * 4);
        short4v sv;
        sv.x = (short)f2bf(((yv[j].x - mu) * rstd * gv.x + bv.x) * zv.x);
        sv.y = (short)f2bf(((yv[j].y - mu) * rstd * gv.y + bv.y) * zv.y);
        sv.z = (short)f2bf(((yv[j].z - mu) * rstd * gv.z + bv.z) * zv.z);
        sv.w = (short)f2bf(((yv[j].w - mu) * rstd * gv.w + bv.w) * zv.w);
        *(short4v*)(grow + j * 4) = sv;
    }
    __syncthreads();
    int wv = t >> 6;
    int lane = t & 63;
    int m = lane & 15, quad = lane >> 4;
    int mt = wv >> 1;
    int nb = (wv & 1) * 3;
    const short* wob = (const short*)Wo_bf;
    short8 a[6];
    #pragma unroll
    for (int kk = 0; kk < 6; ++kk)
        a[kk] = *(const short8*)(sgb + (mt * 16 + m) * GSTRIDE + kk * 32 + quad * 8);
    #pragma unroll
    for (int i = 0; i < 3; ++i) {
        int n0 = (nb + i) * 16;
        f32x4 acc = {0.f, 0.f, 0.f, 0.f};
        #pragma unroll
        for (int kk = 0; kk < 6; ++kk) {
            short8 bfr = *(const short8*)(wob + (size_t)(n0 + m) * 192 + kk * 32 + quad * 8);
            acc = __builtin_amdgcn_mfma_f32_16x16x32_bf16(a[kk], bfr, acc, 0, 0, 0);
        }
        #pragma unroll
        for (int r = 0; r < 4; ++r) {
            int pp = p0 + mt * 16 + quad * 4 + r;
            out[(size_t)pp * 96 + n0 + m] = acc[r];
        }
    }
}

extern "C" void kernel_launch(void* const* d_in, const int* in_sizes, int n_in,
                              void* d_out, int out_size, void* d_ws, size_t ws_size,
                              hipStream_t stream) {
    const float* x    = (const float*)d_in[0];
    const float* W_in = (const float*)d_in[1];
    const float* cw   = (const float*)d_in[2];
    const float* cb   = (const float*)d_in[3];
    const float* xpw  = (const float*)d_in[4];
    const float* dtw  = (const float*)d_in[5];
    const float* dtb  = (const float*)d_in[6];
    const float* Alog = (const float*)d_in[7];
    const float* Ds   = (const float*)d_in[8];
    const float* lng  = (const float*)d_in[9];
    const float* lnb  = (const float*)d_in[10];
    const float* Wout = (const float*)d_in[11];
    float* out = (float*)d_out;

    float* ws = (float*)d_ws;
    size_t off = 0;
    unsigned short* Wi_hi = (unsigned short*)(ws + off); off += 384 * 96 / 2;
    unsigned short* Wi_lo = (unsigned short*)(ws + off); off += 384 * 96 / 2;
    unsigned short* Wo_bf = (unsigned short*)(ws + off); off += 96 * DINNER / 2;
    float* xin   = ws + off; off += (size_t)NPIX * 192;
    float* zbuf  = ws + off; off += (size_t)NPIX * 192;
    float* xg    = ws + off; off += (size_t)NPIX * 192;
    float* dtrb  = ws + off; off += (size_t)NBK * LP * 6;
    float* Bm    = ws + off; off += (size_t)NBK * LP * 16;
    float* Cm    = ws + off; off += (size_t)NBK * LP * 16;
    float* Sbuf  = ws + off; off += (size_t)NCH * SSTRIDE;
    float* QH    = ws + off; off += (size_t)NCH * NSTATES;
    float* yout  = ws + off; off += (size_t)NBK * LP * 192;

    hipLaunchKernelGGL(k_castW, dim3(144), dim3(256), 0, stream,
                       W_in, Wout, Wi_hi, Wi_lo, Wo_bf);
    hipLaunchKernelGGL(k_inproj3, dim3(NPIX / 16), dim3(256), 0, stream,
                       x, Wi_hi, Wi_lo, xin, zbuf);
    hipLaunchKernelGGL(k_conv8, dim3(NPIX / 8), dim3(192), 0, stream,
                       xin, cw, cb, xg);
    hipLaunchKernelGGL(k_xdbl, dim3(NBK * 64), dim3(192), 0, stream,
                       xg, xpw, dtrb, Bm, Cm);
    hipLaunchKernelGGL(k_scan1p, dim3(NBK * NCH), dim3(192), 0, stream,
                       xg, dtrb, Bm, Alog, dtw, dtb, Sbuf, QH);
    hipLaunchKernelGGL(k_scan2, dim3(NSTATES / 256), dim3(256), 0, stream,
                       Sbuf, Alog, QH);
    hipLaunchKernelGGL(k_scan3p, dim3(NBK * NCH), dim3(192), 0, stream,
                       xg, dtrb, Bm, Cm, Alog, dtw, dtb, Ds, QH, yout);
    hipLaunchKernelGGL(k_lnout, dim3(NPIX / 32), dim3(256), 0, stream,
                       yout, zbuf, lng, lnb, Wo_bf, out);
}